// Round 1
// baseline (99.904 us; speedup 1.0000x reference)
//
#include <hip/hip_runtime.h>
#include <math.h>

#define NN 8192
#define TILE 256

// ---------------- scalar reduction indices in ws ----------------
// s[0]  sum_w        (raw snr weights)
// s[1]  sum_w*d^2    (d = p - smoothed)
// s[2]  sum_u
// s[3]  sum_u^2
// s[4]  sum_e        (e = clip(|p-t|,0.001,1))
// s[5]  sum_e^2
// s[6]  sum_u*e
// s[7]  sum relu(0.01-u)
// s[8]  sum relu(u-0.5)
// s[9]  sum_p
// s[10] sum_p^2
// s[11] sum_t
// s[12] sum_t^2
// s[13] sum relu(-p)
// s[14] sum relu(p-1)
// s[15] max_p
// s[16] min_p
// s[17] max_t
// s[18] min_t

__global__ __launch_bounds__(1024) void k_reduce(
    const float* __restrict__ p, const float* __restrict__ t,
    const float* __restrict__ u, const float* __restrict__ snr,
    float* __restrict__ w_out, double* __restrict__ total,
    unsigned long long* __restrict__ count, float* __restrict__ s) {
  const int tid = threadIdx.x;
  if (tid == 0) { *total = 0.0; *count = 0ull; }

  float acc[15];
#pragma unroll
  for (int k = 0; k < 15; ++k) acc[k] = 0.f;
  float mxp = -1e30f, mnp = 1e30f, mxt = -1e30f, mnt = 1e30f;

  for (int i = tid; i < NN; i += 1024) {
    float pi = p[i], ti = t[i], ui = u[i], si = snr[i];
    float wi = 2.f * expf(-si * (1.f / 15.f)) + 0.5f;
    w_out[i] = wi;
    float sm = ti * 0.95f + 0.025f;      // label smoothing
    float d = pi - sm;
    float e = fminf(fmaxf(fabsf(pi - ti), 0.001f), 1.0f);
    acc[0] += wi;
    acc[1] += wi * d * d;
    acc[2] += ui;
    acc[3] += ui * ui;
    acc[4] += e;
    acc[5] += e * e;
    acc[6] += ui * e;
    acc[7] += fmaxf(0.01f - ui, 0.f);
    acc[8] += fmaxf(ui - 0.5f, 0.f);
    acc[9] += pi;
    acc[10] += pi * pi;
    acc[11] += ti;
    acc[12] += ti * ti;
    acc[13] += fmaxf(-pi, 0.f);
    acc[14] += fmaxf(pi - 1.f, 0.f);
    mxp = fmaxf(mxp, pi); mnp = fminf(mnp, pi);
    mxt = fmaxf(mxt, ti); mnt = fminf(mnt, ti);
  }

  float vals[19];
#pragma unroll
  for (int k = 0; k < 15; ++k) vals[k] = acc[k];
  vals[15] = mxp; vals[16] = mnp; vals[17] = mxt; vals[18] = mnt;

  __shared__ float red[16][19];
  const int lane = tid & 63, wv = tid >> 6;
#pragma unroll
  for (int k = 0; k < 19; ++k) {
    float v = vals[k];
    for (int o = 32; o > 0; o >>= 1) {
      float ov = __shfl_down(v, o, 64);
      if (k < 15) v += ov;
      else if (k == 15 || k == 17) v = fmaxf(v, ov);
      else v = fminf(v, ov);
    }
    if (lane == 0) red[wv][k] = v;
  }
  __syncthreads();
  if (tid == 0) {
#pragma unroll
    for (int k = 0; k < 19; ++k) {
      float v = red[0][k];
      for (int w2 = 1; w2 < 16; ++w2) {
        float ov = red[w2][k];
        if (k < 15) v += ov;
        else if (k == 15 || k == 17) v = fmaxf(v, ov);
        else v = fminf(v, ov);
      }
      s[k] = v;
    }
  }
}

// Pairwise hinge ranking over the upper triangle i<j with |t_i-t_j| >= 0.05.
// Accumulates raw (w_i + w_j) * violation (0.5 and the snr-mean normalization
// are applied at finalize).
__device__ __forceinline__ void pair_body(float ti, float pi, float wi,
                                          float tj, float pj, float wj,
                                          float& tot, int& cnt) {
  float td = ti - tj;
  float atd = fabsf(td);
  float pd = pi - pj;
  float m = 0.16f * fminf(fmaxf(atd, 0.1f), 1.0f);  // 2.0 * 0.08 * clip
  // sign(td)*pd via sign-bit xor (td==0 case is masked out by atd<0.05)
  float spd = __uint_as_float(__float_as_uint(pd) ^
                              (__float_as_uint(td) & 0x80000000u));
  float viol = fmaxf(m - spd, 0.f);
  bool c = (atd >= 0.05f);
  tot += c ? (wi + wj) * viol : 0.f;
  cnt += c ? 1 : 0;
}

__global__ __launch_bounds__(256) void k_rank(
    const float* __restrict__ p, const float* __restrict__ t,
    const float* __restrict__ w, double* __restrict__ total,
    unsigned long long* __restrict__ count) {
  const int jc = blockIdx.x, it = blockIdx.y;
  if (jc < it) return;  // upper-triangular tiles only

  __shared__ float4 s_tpw[TILE];
  const int tid = threadIdx.x;
  const int gi = it * TILE + tid;
  const int gj0 = jc * TILE + tid;
  s_tpw[tid] = make_float4(t[gj0], p[gj0], w[gj0], 0.f);
  const float ti = t[gi], pi = p[gi], wi = w[gi];
  __syncthreads();

  float tot = 0.f;
  int cnt = 0;
  if (jc == it) {
    for (int j = tid + 1; j < TILE; ++j) {
      float4 q = s_tpw[j];
      pair_body(ti, pi, wi, q.x, q.y, q.z, tot, cnt);
    }
  } else {
#pragma unroll 4
    for (int j = 0; j < TILE; ++j) {
      float4 q = s_tpw[j];
      pair_body(ti, pi, wi, q.x, q.y, q.z, tot, cnt);
    }
  }

  // block reduce: 4 waves
  const int lane = tid & 63, wv = tid >> 6;
  for (int o = 32; o > 0; o >>= 1) {
    tot += __shfl_down(tot, o, 64);
    cnt += __shfl_down(cnt, o, 64);
  }
  __shared__ float rtot[4];
  __shared__ int rcnt[4];
  if (lane == 0) { rtot[wv] = tot; rcnt[wv] = cnt; }
  __syncthreads();
  if (tid == 0) {
    float bt = rtot[0] + rtot[1] + rtot[2] + rtot[3];
    unsigned long long bc =
        (unsigned long long)(rcnt[0] + rcnt[1] + rcnt[2] + rcnt[3]);
    atomicAdd(total, (double)bt);
    atomicAdd(count, bc);
  }
}

__global__ void k_final(const double* __restrict__ total,
                        const unsigned long long* __restrict__ count,
                        const float* __restrict__ s, float* __restrict__ out) {
  const double inv_n = 1.0 / (double)NN;
  double sum_w = s[0];
  double mean_w = sum_w * inv_n;
  double denom_w = fmax(mean_w, 1e-6);

  double mse = (s[1] * inv_n) / denom_w;

  double rank = 0.0;
  unsigned long long c = *count;
  if (c > 0) rank = (0.5 * (*total) / denom_w) / (double)c;

  double mean_u = s[2] * inv_n, mean_e = s[4] * inv_n;
  double mse_unc = ((double)s[3] - 2.0 * (double)s[6] + (double)s[5]) * inv_n;
  double var_u = fmax(s[3] * inv_n - mean_u * mean_u, 0.0);
  double var_e = fmax(s[5] * inv_n - mean_e * mean_e, 0.0);
  double std_u = fmax(sqrt(var_u), 1e-6);
  double std_e = fmax(sqrt(var_e), 1e-6);
  double cov = s[6] * inv_n - mean_u * mean_e;
  double corr = cov / (std_u * std_e + 1e-6);
  double cl = fmax(0.5 - corr, 0.0);
  double corr_loss = cl * cl;
  double unc_loss =
      0.5 * mse_unc + 0.3 * corr_loss + 0.2 * (fmax(-corr, 0.0) * 10.0);

  double ub_loss = 0.05 * ((s[7] + s[8]) * inv_n);

  double mean_p = s[9] * inv_n, mean_t = s[11] * inv_n;
  double mean_gap = fabs(mean_p - mean_t);
  double max_gap = fmax(1.0 - ((double)s[15] + 1e-6) / ((double)s[17] + 1e-6), 0.0);
  double t_range = (double)s[17] - (double)s[18];
  double p_range = (double)s[15] - (double)s[16];
  double range_pen = fmax(1.0 - (p_range + 1e-6) / (t_range + 1e-6), 0.0);
  double calib = 0.2 * mean_gap + 1.5 * max_gap + 1.0 * range_pen;

  double p_std = sqrt(fmax(s[10] * inv_n - mean_p * mean_p, 0.0));
  double t_std = sqrt(fmax(s[12] * inv_n - mean_t * mean_t, 0.0));
  double var_ratio = p_std / (t_std + 1e-8);
  double minvar = (p_std < 0.5 * t_std && t_std > 1e-4)
                      ? 2.0 * fmax(0.5 - var_ratio, 0.0)
                      : 0.0;

  double bounds_pen = 5.0 * ((s[13] + s[14]) * inv_n);

  // bucket5: eff_mse_w = 0.5*0.85, eff_rank_w = 0.4*1.5
  double tl = 0.425 * mse + 0.6 * rank + 0.35 * unc_loss + ub_loss + calib +
              minvar + bounds_pen;
  out[0] = (float)tl;
}

extern "C" void kernel_launch(void* const* d_in, const int* in_sizes, int n_in,
                              void* d_out, int out_size, void* d_ws,
                              size_t ws_size, hipStream_t stream) {
  const float* p = (const float*)d_in[0];
  const float* t = (const float*)d_in[1];
  const float* u = (const float*)d_in[2];
  const float* snr = (const float*)d_in[3];
  char* ws = (char*)d_ws;
  double* total = (double*)ws;                              // 8 B
  unsigned long long* count = (unsigned long long*)(ws + 8);  // 8 B
  float* s = (float*)(ws + 64);                             // 19 floats
  float* w = (float*)(ws + 4096);                           // 8192 floats

  hipLaunchKernelGGL(k_reduce, dim3(1), dim3(1024), 0, stream,
                     p, t, u, snr, w, total, count, s);
  hipLaunchKernelGGL(k_rank, dim3(32, 32), dim3(256), 0, stream,
                     p, t, w, total, count);
  hipLaunchKernelGGL(k_final, dim3(1), dim3(1), 0, stream,
                     total, count, s, (float*)d_out);
}

// Round 2
// 96.018 us; speedup vs baseline: 1.0405x; 1.0405x over previous
//
#include <hip/hip_runtime.h>
#include <math.h>

#define NN 8192
#define TILE 256
#define NT 32  // NN / TILE

// ---------------- ws layout ----------------
// rank_tot: float[NT*NT]   @ 0      (per-block raw-weighted violation sums)
// rank_cnt: int[NT*NT]     @ 4096   (per-block pair counts)
// red:      float[NT*19]   @ 8192   (per-diag-block elementwise stats)
//
// stat indices k:
// 0 sum_w | 1 sum_w*d^2 | 2 sum_u | 3 sum_u^2 | 4 sum_e | 5 sum_e^2
// 6 sum_u*e | 7 relu(0.01-u) | 8 relu(u-0.5) | 9 sum_p | 10 sum_p^2
// 11 sum_t | 12 sum_t^2 | 13 relu(-p) | 14 relu(p-1)
// 15 max_p | 16 min_p | 17 max_t | 18 min_t

__device__ __forceinline__ void pair_body(float ti, float pi, float wi,
                                          float tj, float pj, float wj,
                                          float& tot, int& cnt) {
  float td = ti - tj;
  float pd = pi - pj;
  float x = fminf(fmaxf(fabsf(td), 0.1f), 1.0f);          // v_med3 w/ abs mod
  // sign(td)*pd via sign-bit xor (td==0 is excluded by the 0.05 mask)
  float spd = __uint_as_float(__float_as_uint(pd) ^
                              (__float_as_uint(td) & 0x80000000u));
  float viol = fmaxf(fmaf(0.16f, x, -spd), 0.f);           // 2*0.08*clip - s*pd
  bool c = (fabsf(td) >= 0.05f);
  tot += c ? (wi + wj) * viol : 0.f;
  cnt += c ? 1 : 0;
}

__global__ __launch_bounds__(256) void k_rank(
    const float* __restrict__ p, const float* __restrict__ t,
    const float* __restrict__ u, const float* __restrict__ snr,
    float* __restrict__ rank_tot, int* __restrict__ rank_cnt,
    float* __restrict__ red) {
  const int jc = blockIdx.x, it = blockIdx.y;
  const int b = it * NT + jc;
  const int tid = threadIdx.x;
  if (jc < it) {  // lower triangle: write identity partials so k_final can sum all
    if (tid == 0) { rank_tot[b] = 0.f; rank_cnt[b] = 0; }
    return;
  }

  __shared__ float4 s_tpw[TILE];
  const int gj = jc * TILE + tid;
  const float tj = t[gj], pj = p[gj];
  const float wjv = 2.f * expf(-snr[gj] * (1.f / 15.f)) + 0.5f;
  s_tpw[tid] = make_float4(tj, pj, wjv, 0.f);

  const bool diag = (it == jc);
  const int gi = it * TILE + tid;
  float ti, pi, wi;
  if (diag) {
    ti = tj; pi = pj; wi = wjv;
  } else {
    ti = t[gi]; pi = p[gi];
    wi = 2.f * expf(-snr[gi] * (1.f / 15.f)) + 0.5f;
  }
  __syncthreads();

  float tot = 0.f;
  int cnt = 0;
  if (diag) {
    for (int j = tid + 1; j < TILE; ++j) {
      float4 q = s_tpw[j];
      pair_body(ti, pi, wi, q.x, q.y, q.z, tot, cnt);
    }
  } else {
#pragma unroll 8
    for (int j = 0; j < TILE; ++j) {
      float4 q = s_tpw[j];
      pair_body(ti, pi, wi, q.x, q.y, q.z, tot, cnt);
    }
  }

  // block reduce tot/cnt across 4 waves
  const int lane = tid & 63, wv = tid >> 6;
  for (int o = 32; o > 0; o >>= 1) {
    tot += __shfl_down(tot, o, 64);
    cnt += __shfl_down(cnt, o, 64);
  }
  __shared__ float rtot[4];
  __shared__ int rcnt[4];
  if (lane == 0) { rtot[wv] = tot; rcnt[wv] = cnt; }
  __syncthreads();
  if (tid == 0) {
    rank_tot[b] = rtot[0] + rtot[1] + rtot[2] + rtot[3];
    rank_cnt[b] = rcnt[0] + rcnt[1] + rcnt[2] + rcnt[3];
  }

  // diagonal blocks additionally compute the elementwise stats for their slice
  if (diag) {
    const float ui = u[gi];
    const float sm = ti * 0.95f + 0.025f;  // label smoothing
    const float d = pi - sm;
    const float e = fminf(fmaxf(fabsf(pi - ti), 0.001f), 1.0f);
    float v[19];
    v[0] = wi;            v[1] = wi * d * d;
    v[2] = ui;            v[3] = ui * ui;
    v[4] = e;             v[5] = e * e;
    v[6] = ui * e;
    v[7] = fmaxf(0.01f - ui, 0.f);
    v[8] = fmaxf(ui - 0.5f, 0.f);
    v[9] = pi;            v[10] = pi * pi;
    v[11] = ti;           v[12] = ti * ti;
    v[13] = fmaxf(-pi, 0.f);
    v[14] = fmaxf(pi - 1.f, 0.f);
    v[15] = pi; v[16] = pi; v[17] = ti; v[18] = ti;

    __shared__ float sred[4][19];
#pragma unroll
    for (int k = 0; k < 19; ++k) {
      float x = v[k];
      for (int o = 32; o > 0; o >>= 1) {
        float ox = __shfl_down(x, o, 64);
        if (k < 15) x += ox;
        else if (k == 15 || k == 17) x = fmaxf(x, ox);
        else x = fminf(x, ox);
      }
      if (lane == 0) sred[wv][k] = x;
    }
    __syncthreads();
    if (tid == 0) {
#pragma unroll
      for (int k = 0; k < 19; ++k) {
        float x = sred[0][k];
        for (int w2 = 1; w2 < 4; ++w2) {
          float ox = sred[w2][k];
          if (k < 15) x += ox;
          else if (k == 15 || k == 17) x = fmaxf(x, ox);
          else x = fminf(x, ox);
        }
        red[it * 19 + k] = x;
      }
    }
  }
}

__global__ __launch_bounds__(256) void k_final(
    const float* __restrict__ rank_tot, const int* __restrict__ rank_cnt,
    const float* __restrict__ red, float* __restrict__ out) {
  const int tid = threadIdx.x;
  double dt = 0.0;
  long long dc = 0;
  for (int i = tid; i < NT * NT; i += 256) {
    dt += (double)rank_tot[i];
    dc += (long long)rank_cnt[i];
  }
  const int lane = tid & 63, wv = tid >> 6;
  for (int o = 32; o > 0; o >>= 1) {
    dt += __shfl_down(dt, o, 64);
    dc += __shfl_down(dc, o, 64);
  }
  __shared__ double sdt[4];
  __shared__ long long sdc[4];
  if (lane == 0) { sdt[wv] = dt; sdc[wv] = dc; }

  __shared__ double sfin[19];
  if (tid < 19) {
    const int k = tid;
    double x;
    if (k < 15) {
      x = 0.0;
      for (int b2 = 0; b2 < NT; ++b2) x += (double)red[b2 * 19 + k];
    } else if (k == 15 || k == 17) {
      x = -1e30;
      for (int b2 = 0; b2 < NT; ++b2) x = fmax(x, (double)red[b2 * 19 + k]);
    } else {
      x = 1e30;
      for (int b2 = 0; b2 < NT; ++b2) x = fmin(x, (double)red[b2 * 19 + k]);
    }
    sfin[k] = x;
  }
  __syncthreads();

  if (tid == 0) {
    const double total = sdt[0] + sdt[1] + sdt[2] + sdt[3];
    const long long c = sdc[0] + sdc[1] + sdc[2] + sdc[3];
    const double inv_n = 1.0 / (double)NN;

    double mean_w = sfin[0] * inv_n;
    double denom_w = fmax(mean_w, 1e-6);

    double mse = (sfin[1] * inv_n) / denom_w;

    double rank = 0.0;
    if (c > 0) rank = (0.5 * total / denom_w) / (double)c;

    double mean_u = sfin[2] * inv_n, mean_e = sfin[4] * inv_n;
    double mse_unc = (sfin[3] - 2.0 * sfin[6] + sfin[5]) * inv_n;
    double var_u = fmax(sfin[3] * inv_n - mean_u * mean_u, 0.0);
    double var_e = fmax(sfin[5] * inv_n - mean_e * mean_e, 0.0);
    double std_u = fmax(sqrt(var_u), 1e-6);
    double std_e = fmax(sqrt(var_e), 1e-6);
    double cov = sfin[6] * inv_n - mean_u * mean_e;
    double corr = cov / (std_u * std_e + 1e-6);
    double cl = fmax(0.5 - corr, 0.0);
    double unc_loss =
        0.5 * mse_unc + 0.3 * cl * cl + 0.2 * (fmax(-corr, 0.0) * 10.0);

    double ub_loss = 0.05 * ((sfin[7] + sfin[8]) * inv_n);

    double mean_p = sfin[9] * inv_n, mean_t = sfin[11] * inv_n;
    double mean_gap = fabs(mean_p - mean_t);
    double max_gap = fmax(1.0 - (sfin[15] + 1e-6) / (sfin[17] + 1e-6), 0.0);
    double t_range = sfin[17] - sfin[18];
    double p_range = sfin[15] - sfin[16];
    double range_pen = fmax(1.0 - (p_range + 1e-6) / (t_range + 1e-6), 0.0);
    double calib = 0.2 * mean_gap + 1.5 * max_gap + 1.0 * range_pen;

    double p_std = sqrt(fmax(sfin[10] * inv_n - mean_p * mean_p, 0.0));
    double t_std = sqrt(fmax(sfin[12] * inv_n - mean_t * mean_t, 0.0));
    double var_ratio = p_std / (t_std + 1e-8);
    double minvar = (p_std < 0.5 * t_std && t_std > 1e-4)
                        ? 2.0 * fmax(0.5 - var_ratio, 0.0)
                        : 0.0;

    double bounds_pen = 5.0 * ((sfin[13] + sfin[14]) * inv_n);

    // bucket5: eff_mse_w = 0.5*0.85 = 0.425, eff_rank_w = 0.4*1.5 = 0.6
    double tl = 0.425 * mse + 0.6 * rank + 0.35 * unc_loss + ub_loss + calib +
                minvar + bounds_pen;
    out[0] = (float)tl;
  }
}

extern "C" void kernel_launch(void* const* d_in, const int* in_sizes, int n_in,
                              void* d_out, int out_size, void* d_ws,
                              size_t ws_size, hipStream_t stream) {
  const float* p = (const float*)d_in[0];
  const float* t = (const float*)d_in[1];
  const float* u = (const float*)d_in[2];
  const float* snr = (const float*)d_in[3];
  char* ws = (char*)d_ws;
  float* rank_tot = (float*)ws;            // 4096 B
  int* rank_cnt = (int*)(ws + 4096);       // 4096 B
  float* red = (float*)(ws + 8192);        // 32*19 floats

  hipLaunchKernelGGL(k_rank, dim3(NT, NT), dim3(256), 0, stream,
                     p, t, u, snr, rank_tot, rank_cnt, red);
  hipLaunchKernelGGL(k_final, dim3(1), dim3(256), 0, stream,
                     rank_tot, rank_cnt, red, (float*)d_out);
}